// Round 1
// baseline (10827.386 us; speedup 1.0000x reference)
//
#include <hip/hip_runtime.h>
#include <hip/hip_bf16.h>

#define N_NODES 100000
#define N_EDGES 3200000
#define D 256

using bf16x8 = __attribute__((ext_vector_type(8))) short;
using f32x4  = __attribute__((ext_vector_type(4))) float;

__device__ inline float bf2f(unsigned short b) {
    union { unsigned u; float f; } v; v.u = ((unsigned)b) << 16; return v.f;
}
__device__ inline unsigned short f2bf(float f) {
    union { float f; unsigned u; } v; v.f = f;
    unsigned u = v.u;
    u += 0x7FFFu + ((u >> 16) & 1u);   // round-to-nearest-even
    return (unsigned short)(u >> 16);
}

// ---- W fp32 -> bf16 ----
__global__ __launch_bounds__(256) void cvt_w(const float* __restrict__ src,
                                             unsigned short* __restrict__ dst, int n) {
    int i = (blockIdx.x * blockDim.x + threadIdx.x) * 4;
    if (i >= n) return;
    float4 f = *(const float4*)(src + i);
    ushort4 o;
    o.x = f2bf(f.x); o.y = f2bf(f.y); o.z = f2bf(f.z); o.w = f2bf(f.w);
    *(ushort4*)(dst + i) = o;
}

// ---- support = X @ W^T, bf16 MFMA, fused fp32->bf16 conversion of x ----
// One wave computes a 16(M) x 256(N) strip. A-frag: A[m=lane&15][k=quad*8+j];
// B-frag: B[k=quad*8+j][n=lane&15] with B[k][n] = W[n][k] (row-major W, contiguous k).
// C/D: col=lane&15, row=quad*4+reg.
__global__ __launch_bounds__(256) void gemm_xwT(
    const float* __restrict__ x,            // [M, 256] fp32
    const unsigned short* __restrict__ wb,  // [256, 256] bf16
    unsigned short* __restrict__ sb,        // [M, 256] bf16 out
    int M)
{
    int wave = (int)((blockIdx.x * blockDim.x + threadIdx.x) >> 6);
    int lane = threadIdx.x & 63;
    int m0 = wave << 4;
    if (m0 >= M) return;
    int quad = lane >> 4;
    int r16  = lane & 15;

    const float* arow = x + (size_t)(m0 + r16) * D + quad * 8;
    const unsigned short* bbase = wb + (size_t)r16 * D + quad * 8;

    f32x4 acc[16];
#pragma unroll
    for (int t = 0; t < 16; ++t) acc[t] = (f32x4){0.f, 0.f, 0.f, 0.f};

    for (int k0 = 0; k0 < D; k0 += 32) {
        float4 fa0 = *(const float4*)(arow + k0);
        float4 fa1 = *(const float4*)(arow + k0 + 4);
        bf16x8 a;
        a[0] = (short)f2bf(fa0.x); a[1] = (short)f2bf(fa0.y);
        a[2] = (short)f2bf(fa0.z); a[3] = (short)f2bf(fa0.w);
        a[4] = (short)f2bf(fa1.x); a[5] = (short)f2bf(fa1.y);
        a[6] = (short)f2bf(fa1.z); a[7] = (short)f2bf(fa1.w);
#pragma unroll
        for (int t = 0; t < 16; ++t) {
            bf16x8 b = *(const bf16x8*)(bbase + (size_t)t * 16 * D + k0);
            acc[t] = __builtin_amdgcn_mfma_f32_16x16x32_bf16(a, b, acc[t], 0, 0, 0);
        }
    }

#pragma unroll
    for (int t = 0; t < 16; ++t) {
#pragma unroll
        for (int r = 0; r < 4; ++r) {
            int row = m0 + quad * 4 + r;
            int col = t * 16 + r16;
            sb[(size_t)row * D + col] = f2bf(acc[t][r]);
        }
    }
}

// ---- SpMM scatter: one wave per edge, 4 floats/lane, fp32 atomics ----
__global__ __launch_bounds__(256) void spmm_atomic(
    const int* __restrict__ erow, const int* __restrict__ ecol,
    const float* __restrict__ eval, const unsigned short* __restrict__ sb,
    float* __restrict__ out)
{
    int wave = (int)((blockIdx.x * blockDim.x + threadIdx.x) >> 6);
    int lane = threadIdx.x & 63;
    if (wave >= N_EDGES) return;
    int   r = erow[wave];
    int   c = ecol[wave];
    float v = eval[wave];
    ushort4 s = *(const ushort4*)(sb + (size_t)c * D + lane * 4);
    float* o = out + (size_t)r * D + lane * 4;
    atomicAdd(o + 0, v * bf2f(s.x));
    atomicAdd(o + 1, v * bf2f(s.y));
    atomicAdd(o + 2, v * bf2f(s.z));
    atomicAdd(o + 3, v * bf2f(s.w));
}

extern "C" void kernel_launch(void* const* d_in, const int* in_sizes, int n_in,
                              void* d_out, int out_size, void* d_ws, size_t ws_size,
                              hipStream_t stream) {
    const float* x    = (const float*)d_in[0];
    const float* W    = (const float*)d_in[1];
    const int*   erow = (const int*)d_in[2];
    const int*   ecol = (const int*)d_in[3];
    const float* eval = (const float*)d_in[4];
    float* out = (float*)d_out;

    // workspace layout
    unsigned short* wb = (unsigned short*)d_ws;                       // 128 KB
    unsigned short* sb = (unsigned short*)((char*)d_ws + 131072);     // 51.2 MB

    hipMemsetAsync(d_out, 0, (size_t)out_size * sizeof(float), stream);

    cvt_w<<<(D * D / 4 + 255) / 256, 256, 0, stream>>>(W, wb, D * D);

    int waves = N_NODES / 16;  // 6250, exact
    gemm_xwT<<<(waves + 3) / 4, 256, 0, stream>>>(x, wb, sb, N_NODES);

    spmm_atomic<<<(N_EDGES + 3) / 4, 256, 0, stream>>>(erow, ecol, eval, sb, out);
}

// Round 2
// 974.461 us; speedup vs baseline: 11.1112x; 11.1112x over previous
//
#include <hip/hip_runtime.h>
#include <hip/hip_bf16.h>

#define N_NODES 100000
#define N_EDGES 3200000
#define D 256

using bf16x8 = __attribute__((ext_vector_type(8))) short;
using f32x4  = __attribute__((ext_vector_type(4))) float;

__device__ inline float bf2f(unsigned short b) {
    union { unsigned u; float f; } v; v.u = ((unsigned)b) << 16; return v.f;
}
__device__ inline unsigned short f2bf(float f) {
    union { float f; unsigned u; } v; v.f = f;
    unsigned u = v.u;
    u += 0x7FFFu + ((u >> 16) & 1u);   // round-to-nearest-even
    return (unsigned short)(u >> 16);
}

// ---- W fp32 -> bf16 ----
__global__ __launch_bounds__(256) void cvt_w(const float* __restrict__ src,
                                             unsigned short* __restrict__ dst, int n) {
    int i = (blockIdx.x * blockDim.x + threadIdx.x) * 4;
    if (i >= n) return;
    float4 f = *(const float4*)(src + i);
    ushort4 o;
    o.x = f2bf(f.x); o.y = f2bf(f.y); o.z = f2bf(f.z); o.w = f2bf(f.w);
    *(ushort4*)(dst + i) = o;
}

// ---- support = X @ W^T, bf16 MFMA, fused fp32->bf16 conversion of x ----
__global__ __launch_bounds__(256) void gemm_xwT(
    const float* __restrict__ x,            // [M, 256] fp32
    const unsigned short* __restrict__ wb,  // [256, 256] bf16
    unsigned short* __restrict__ sb,        // [M, 256] bf16 out
    int M)
{
    int wave = (int)((blockIdx.x * blockDim.x + threadIdx.x) >> 6);
    int lane = threadIdx.x & 63;
    int m0 = wave << 4;
    if (m0 >= M) return;
    int quad = lane >> 4;
    int r16  = lane & 15;

    const float* arow = x + (size_t)(m0 + r16) * D + quad * 8;
    const unsigned short* bbase = wb + (size_t)r16 * D + quad * 8;

    f32x4 acc[16];
#pragma unroll
    for (int t = 0; t < 16; ++t) acc[t] = (f32x4){0.f, 0.f, 0.f, 0.f};

    for (int k0 = 0; k0 < D; k0 += 32) {
        float4 fa0 = *(const float4*)(arow + k0);
        float4 fa1 = *(const float4*)(arow + k0 + 4);
        bf16x8 a;
        a[0] = (short)f2bf(fa0.x); a[1] = (short)f2bf(fa0.y);
        a[2] = (short)f2bf(fa0.z); a[3] = (short)f2bf(fa0.w);
        a[4] = (short)f2bf(fa1.x); a[5] = (short)f2bf(fa1.y);
        a[6] = (short)f2bf(fa1.z); a[7] = (short)f2bf(fa1.w);
#pragma unroll
        for (int t = 0; t < 16; ++t) {
            bf16x8 b = *(const bf16x8*)(bbase + (size_t)t * 16 * D + k0);
            acc[t] = __builtin_amdgcn_mfma_f32_16x16x32_bf16(a, b, acc[t], 0, 0, 0);
        }
    }

#pragma unroll
    for (int t = 0; t < 16; ++t) {
#pragma unroll
        for (int r = 0; r < 4; ++r) {
            int row = m0 + quad * 4 + r;
            int col = t * 16 + r16;
            sb[(size_t)row * D + col] = f2bf(acc[t][r]);
        }
    }
}

// ================= CSR build =================

__global__ __launch_bounds__(256) void hist_rows(const int* __restrict__ erow,
                                                 int* __restrict__ cnt) {
    int e = blockIdx.x * 256 + threadIdx.x;
    if (e < N_EDGES) atomicAdd(&cnt[erow[e]], 1);
}

// per-block inclusive scan of cnt -> incl, block sums -> bsums
__global__ __launch_bounds__(256) void scan_block(const int* __restrict__ cnt,
                                                  int* __restrict__ incl,
                                                  int* __restrict__ bsums, int n) {
    __shared__ int lds[256];
    int i = blockIdx.x * 256 + threadIdx.x;
    int v = (i < n) ? cnt[i] : 0;
    lds[threadIdx.x] = v;
    __syncthreads();
    for (int off = 1; off < 256; off <<= 1) {
        int t = (threadIdx.x >= (unsigned)off) ? lds[threadIdx.x - off] : 0;
        __syncthreads();
        lds[threadIdx.x] += t;
        __syncthreads();
    }
    if (i < n) incl[i] = lds[threadIdx.x];
    if (threadIdx.x == 255) bsums[blockIdx.x] = lds[255];
}

// single block: bsums -> exclusive prefix (in place); nb <= 512
__global__ __launch_bounds__(512) void scan_sums(int* __restrict__ bsums, int nb) {
    __shared__ int lds[512];
    int v = (threadIdx.x < (unsigned)nb) ? bsums[threadIdx.x] : 0;
    lds[threadIdx.x] = v;
    __syncthreads();
    for (int off = 1; off < 512; off <<= 1) {
        int t = (threadIdx.x >= (unsigned)off) ? lds[threadIdx.x - off] : 0;
        __syncthreads();
        lds[threadIdx.x] += t;
        __syncthreads();
    }
    if (threadIdx.x < (unsigned)nb) bsums[threadIdx.x] = lds[threadIdx.x] - v;
}

__global__ __launch_bounds__(256) void finalize_scan(
    const int* __restrict__ cnt, const int* __restrict__ incl,
    const int* __restrict__ bsums, int* __restrict__ rowptr,
    int* __restrict__ next, int n) {
    int i = blockIdx.x * 256 + threadIdx.x;
    if (i >= n) return;
    int g = incl[i] + bsums[blockIdx.x];   // global inclusive
    rowptr[i + 1] = g;
    next[i] = g - cnt[i];                  // global exclusive
    if (i == 0) rowptr[0] = 0;
}

__global__ __launch_bounds__(256) void scatter_edges(
    const int* __restrict__ erow, const int* __restrict__ ecol,
    const float* __restrict__ eval, int* __restrict__ next,
    int2* __restrict__ csr) {
    int e = blockIdx.x * 256 + threadIdx.x;
    if (e >= N_EDGES) return;
    int r = erow[e];
    int pos = atomicAdd(&next[r], 1);
    int2 p;
    p.x = ecol[e];
    p.y = __float_as_int(eval[e]);
    csr[pos] = p;
}

// ================= gather SpMM =================
// One wave per output row; lane holds cols [lane*4, lane*4+4).
__global__ __launch_bounds__(256) void spmm_gather(
    const int* __restrict__ rowptr, const int2* __restrict__ csr,
    const unsigned short* __restrict__ sb, float* __restrict__ out) {
    int wave = (int)((blockIdx.x * blockDim.x + threadIdx.x) >> 6);
    int lane = threadIdx.x & 63;
    if (wave >= N_NODES) return;
    int beg = rowptr[wave], end = rowptr[wave + 1];
    float4 acc = {0.f, 0.f, 0.f, 0.f};
    const unsigned short* base = sb + lane * 4;
    for (int e = beg; e < end; ++e) {
        int2 p = csr[e];
        float v = __int_as_float(p.y);
        ushort4 s = *(const ushort4*)(base + ((size_t)p.x << 8));
        acc.x += v * bf2f(s.x);
        acc.y += v * bf2f(s.y);
        acc.z += v * bf2f(s.z);
        acc.w += v * bf2f(s.w);
    }
    *(float4*)(out + (size_t)wave * D + lane * 4) = acc;
}

extern "C" void kernel_launch(void* const* d_in, const int* in_sizes, int n_in,
                              void* d_out, int out_size, void* d_ws, size_t ws_size,
                              hipStream_t stream) {
    const float* x    = (const float*)d_in[0];
    const float* W    = (const float*)d_in[1];
    const int*   erow = (const int*)d_in[2];
    const int*   ecol = (const int*)d_in[3];
    const float* eval = (const float*)d_in[4];
    float* out = (float*)d_out;

    // ---- workspace layout (bytes) ----
    char* ws = (char*)d_ws;
    unsigned short* wb     = (unsigned short*)(ws + 0);           // 131072
    unsigned short* sb     = (unsigned short*)(ws + 131072);      // 51,200,000
    int*            cnt    = (int*)(ws + 51331072);               // 400,000
    int*            incl   = (int*)(ws + 51731072);               // 400,000
    int*            rowptr = (int*)(ws + 52131072);               // 400,004
    int*            next   = (int*)(ws + 52531200);               // 400,000
    int*            bsums  = (int*)(ws + 52931200);               // 2,048
    int2*           csr    = (int2*)(ws + 52933632);              // 25,600,000
    // total ~78.6 MB

    const int nb = (N_NODES + 255) / 256;  // 391 scan blocks

    // ---- CSR build ----
    hipMemsetAsync(cnt, 0, N_NODES * sizeof(int), stream);
    hist_rows<<<(N_EDGES + 255) / 256, 256, 0, stream>>>(erow, cnt);
    scan_block<<<nb, 256, 0, stream>>>(cnt, incl, bsums, N_NODES);
    scan_sums<<<1, 512, 0, stream>>>(bsums, nb);
    finalize_scan<<<nb, 256, 0, stream>>>(cnt, incl, bsums, rowptr, next, N_NODES);
    scatter_edges<<<(N_EDGES + 255) / 256, 256, 0, stream>>>(erow, ecol, eval, next, csr);

    // ---- GEMM (support = X W^T, bf16) ----
    cvt_w<<<(D * D / 4 + 255) / 256, 256, 0, stream>>>(W, wb, D * D);
    int waves = N_NODES / 16;  // 6250
    gemm_xwT<<<(waves + 3) / 4, 256, 0, stream>>>(x, wb, sb, N_NODES);

    // ---- gather SpMM (writes every output row; no memset needed) ----
    spmm_gather<<<(N_NODES + 3) / 4, 256, 0, stream>>>(rowptr, csr, sb, out);
}

// Round 4
// 817.318 us; speedup vs baseline: 13.2475x; 1.1923x over previous
//
#include <hip/hip_runtime.h>
#include <hip/hip_bf16.h>

#define N_NODES 100000
#define N_EDGES 3200000
#define D 256
#define N_STRIPES 8
#define STRIPE ((N_NODES + N_STRIPES - 1) / N_STRIPES)   // 12500

using bf16x8 = __attribute__((ext_vector_type(8))) short;
using f32x4  = __attribute__((ext_vector_type(4))) float;

__device__ inline float bf2f(unsigned short b) {
    union { unsigned u; float f; } v; v.u = ((unsigned)b) << 16; return v.f;
}
__device__ inline unsigned short f2bf(float f) {
    union { float f; unsigned u; } v; v.f = f;
    unsigned u = v.u;
    u += 0x7FFFu + ((u >> 16) & 1u);   // round-to-nearest-even
    return (unsigned short)(u >> 16);
}

// ---- W fp32 -> bf16 ----
__global__ __launch_bounds__(256) void cvt_w(const float* __restrict__ src,
                                             unsigned short* __restrict__ dst, int n) {
    int i = (blockIdx.x * blockDim.x + threadIdx.x) * 4;
    if (i >= n) return;
    float4 f = *(const float4*)(src + i);
    ushort4 o;
    o.x = f2bf(f.x); o.y = f2bf(f.y); o.z = f2bf(f.z); o.w = f2bf(f.w);
    *(ushort4*)(dst + i) = o;
}

// ---- support = X @ W^T, bf16 MFMA, fused fp32->bf16 conversion of x ----
__global__ __launch_bounds__(256) void gemm_xwT(
    const float* __restrict__ x,            // [M, 256] fp32
    const unsigned short* __restrict__ wb,  // [256, 256] bf16
    unsigned short* __restrict__ sb,        // [M, 256] bf16 out
    int M)
{
    int wave = (int)((blockIdx.x * blockDim.x + threadIdx.x) >> 6);
    int lane = threadIdx.x & 63;
    int m0 = wave << 4;
    if (m0 >= M) return;
    int quad = lane >> 4;
    int r16  = lane & 15;

    const f32x4* arow = (const f32x4*)(x + (size_t)(m0 + r16) * D + quad * 8);
    const unsigned short* bbase = wb + (size_t)r16 * D + quad * 8;

    f32x4 acc[16];
#pragma unroll
    for (int t = 0; t < 16; ++t) acc[t] = (f32x4){0.f, 0.f, 0.f, 0.f};

    for (int k0 = 0; k0 < D; k0 += 32) {
        // x is read exactly once per call -> non-temporal (keep L3 for support)
        f32x4 fa0 = __builtin_nontemporal_load(arow + (k0 >> 2));
        f32x4 fa1 = __builtin_nontemporal_load(arow + (k0 >> 2) + 1);
        bf16x8 a;
        a[0] = (short)f2bf(fa0[0]); a[1] = (short)f2bf(fa0[1]);
        a[2] = (short)f2bf(fa0[2]); a[3] = (short)f2bf(fa0[3]);
        a[4] = (short)f2bf(fa1[0]); a[5] = (short)f2bf(fa1[1]);
        a[6] = (short)f2bf(fa1[2]); a[7] = (short)f2bf(fa1[3]);
#pragma unroll
        for (int t = 0; t < 16; ++t) {
            bf16x8 b = *(const bf16x8*)(bbase + (size_t)t * 16 * D + k0);
            acc[t] = __builtin_amdgcn_mfma_f32_16x16x32_bf16(a, b, acc[t], 0, 0, 0);
        }
    }

#pragma unroll
    for (int t = 0; t < 16; ++t) {
#pragma unroll
        for (int r = 0; r < 4; ++r) {
            int row = m0 + quad * 4 + r;
            int col = t * 16 + r16;
            sb[(size_t)row * D + col] = f2bf(acc[t][r]);
        }
    }
}

// ================= CSR build =================

__global__ __launch_bounds__(256) void hist_rows(const int* __restrict__ erow,
                                                 int* __restrict__ cnt) {
    int e = blockIdx.x * 256 + threadIdx.x;
    if (e < N_EDGES) atomicAdd(&cnt[erow[e]], 1);
}

// per-block inclusive scan of cnt -> incl, block sums -> bsums
__global__ __launch_bounds__(256) void scan_block(const int* __restrict__ cnt,
                                                  int* __restrict__ incl,
                                                  int* __restrict__ bsums, int n) {
    __shared__ int lds[256];
    int i = blockIdx.x * 256 + threadIdx.x;
    int v = (i < n) ? cnt[i] : 0;
    lds[threadIdx.x] = v;
    __syncthreads();
    for (int off = 1; off < 256; off <<= 1) {
        int t = (threadIdx.x >= (unsigned)off) ? lds[threadIdx.x - off] : 0;
        __syncthreads();
        lds[threadIdx.x] += t;
        __syncthreads();
    }
    if (i < n) incl[i] = lds[threadIdx.x];
    if (threadIdx.x == 255) bsums[blockIdx.x] = lds[255];
}

// single block: bsums -> exclusive prefix (in place); nb <= 512
__global__ __launch_bounds__(512) void scan_sums(int* __restrict__ bsums, int nb) {
    __shared__ int lds[512];
    int v = (threadIdx.x < (unsigned)nb) ? bsums[threadIdx.x] : 0;
    lds[threadIdx.x] = v;
    __syncthreads();
    for (int off = 1; off < 512; off <<= 1) {
        int t = (threadIdx.x >= (unsigned)off) ? lds[threadIdx.x - off] : 0;
        __syncthreads();
        lds[threadIdx.x] += t;
        __syncthreads();
    }
    if (threadIdx.x < (unsigned)nb) bsums[threadIdx.x] = lds[threadIdx.x] - v;
}

__global__ __launch_bounds__(256) void finalize_scan(
    const int* __restrict__ cnt, const int* __restrict__ incl,
    const int* __restrict__ bsums, int* __restrict__ rowptr,
    int* __restrict__ next, int n) {
    int i = blockIdx.x * 256 + threadIdx.x;
    if (i >= n) return;
    int g = incl[i] + bsums[blockIdx.x];   // global inclusive
    rowptr[i + 1] = g;
    next[i] = g - cnt[i];                  // global exclusive
    if (i == 0) rowptr[0] = 0;
}

// striped scatter: blockIdx.y = stripe; only edges whose row falls in the
// stripe are written. Each stripe's csr segment is ~3.2 MB -> L2-resident,
// so the 8B partial-line writes coalesce in L2 instead of thrashing HBM.
__global__ __launch_bounds__(256) void scatter_striped(
    const int* __restrict__ erow, const int* __restrict__ ecol,
    const float* __restrict__ eval, int* __restrict__ next,
    int2* __restrict__ csr) {
    int e = blockIdx.x * 256 + threadIdx.x;
    if (e >= N_EDGES) return;
    int r = erow[e];
    int lo = (int)blockIdx.y * STRIPE;
    if (r >= lo && r < lo + STRIPE) {
        int pos = atomicAdd(&next[r], 1);
        int2 p;
        p.x = ecol[e];
        p.y = __float_as_int(eval[e]);
        csr[pos] = p;
    }
}

// ================= gather SpMM =================
// One wave per output row; lane holds cols [lane*4, lane*4+4).
__global__ __launch_bounds__(256) void spmm_gather(
    const int* __restrict__ rowptr, const int2* __restrict__ csr,
    const unsigned short* __restrict__ sb, float* __restrict__ out) {
    int wave = (int)((blockIdx.x * blockDim.x + threadIdx.x) >> 6);
    int lane = threadIdx.x & 63;
    if (wave >= N_NODES) return;
    int beg = rowptr[wave], end = rowptr[wave + 1];
    f32x4 acc0 = {0.f, 0.f, 0.f, 0.f};
    f32x4 acc1 = {0.f, 0.f, 0.f, 0.f};
    const unsigned short* base = sb + lane * 4;
    int e = beg;
    for (; e + 1 < end; e += 2) {
        int2 p0 = csr[e];
        int2 p1 = csr[e + 1];
        float v0 = __int_as_float(p0.y);
        float v1 = __int_as_float(p1.y);
        ushort4 s0 = *(const ushort4*)(base + ((size_t)p0.x << 8));
        ushort4 s1 = *(const ushort4*)(base + ((size_t)p1.x << 8));
        acc0[0] += v0 * bf2f(s0.x); acc0[1] += v0 * bf2f(s0.y);
        acc0[2] += v0 * bf2f(s0.z); acc0[3] += v0 * bf2f(s0.w);
        acc1[0] += v1 * bf2f(s1.x); acc1[1] += v1 * bf2f(s1.y);
        acc1[2] += v1 * bf2f(s1.z); acc1[3] += v1 * bf2f(s1.w);
    }
    if (e < end) {
        int2 p = csr[e];
        float v = __int_as_float(p.y);
        ushort4 s = *(const ushort4*)(base + ((size_t)p.x << 8));
        acc0[0] += v * bf2f(s.x); acc0[1] += v * bf2f(s.y);
        acc0[2] += v * bf2f(s.z); acc0[3] += v * bf2f(s.w);
    }
    f32x4 r = acc0 + acc1;
    // out is written once and never read -> non-temporal, keep L3 for support
    __builtin_nontemporal_store(r, (f32x4*)(out + (size_t)wave * D + lane * 4));
}

extern "C" void kernel_launch(void* const* d_in, const int* in_sizes, int n_in,
                              void* d_out, int out_size, void* d_ws, size_t ws_size,
                              hipStream_t stream) {
    const float* x    = (const float*)d_in[0];
    const float* W    = (const float*)d_in[1];
    const int*   erow = (const int*)d_in[2];
    const int*   ecol = (const int*)d_in[3];
    const float* eval = (const float*)d_in[4];
    float* out = (float*)d_out;

    // ---- workspace layout (bytes) ----
    char* ws = (char*)d_ws;
    unsigned short* wb     = (unsigned short*)(ws + 0);           // 131072
    unsigned short* sb     = (unsigned short*)(ws + 131072);      // 51,200,000
    int*            cnt    = (int*)(ws + 51331072);               // 400,000
    int*            incl   = (int*)(ws + 51731072);               // 400,000
    int*            rowptr = (int*)(ws + 52131072);               // 400,004
    int*            next   = (int*)(ws + 52531200);               // 400,000
    int*            bsums  = (int*)(ws + 52931200);               // 2,048
    int2*           csr    = (int2*)(ws + 52933632);              // 25,600,000
    // total ~78.6 MB

    const int nb = (N_NODES + 255) / 256;  // 391 scan blocks

    // ---- CSR build ----
    hipMemsetAsync(cnt, 0, N_NODES * sizeof(int), stream);
    hist_rows<<<(N_EDGES + 255) / 256, 256, 0, stream>>>(erow, cnt);
    scan_block<<<nb, 256, 0, stream>>>(cnt, incl, bsums, N_NODES);
    scan_sums<<<1, 512, 0, stream>>>(bsums, nb);
    finalize_scan<<<nb, 256, 0, stream>>>(cnt, incl, bsums, rowptr, next, N_NODES);
    {
        dim3 g((N_EDGES + 255) / 256, N_STRIPES, 1);
        scatter_striped<<<g, 256, 0, stream>>>(erow, ecol, eval, next, csr);
    }

    // ---- GEMM (support = X W^T, bf16) ----
    cvt_w<<<(D * D / 4 + 255) / 256, 256, 0, stream>>>(W, wb, D * D);
    int waves = N_NODES / 16;  // 6250
    gemm_xwT<<<(waves + 3) / 4, 256, 0, stream>>>(x, wb, sb, N_NODES);

    // ---- gather SpMM (writes every output row; no memset needed) ----
    spmm_gather<<<(N_NODES + 3) / 4, 256, 0, stream>>>(rowptr, csr, sb, out);
}

// Round 5
// 800.511 us; speedup vs baseline: 13.5256x; 1.0210x over previous
//
#include <hip/hip_runtime.h>
#include <hip/hip_bf16.h>

#define N_NODES 100000
#define N_EDGES 3200000
#define D 256
#define N_STRIPES 8
#define STRIPE 12500

#define HIST_BLOCKS 3125   // 3.2M edges / (256 thr * 4 edges)
#define GEMM_BLOCKS 1563   // 6250 waves / 4
#define CVT_BLOCKS  64     // 65536 W elems / (256*4)
#define ZERO_BLOCKS 98     // 25000 int4 / 256

using bf16x8 = __attribute__((ext_vector_type(8))) short;
using f32x4  = __attribute__((ext_vector_type(4))) float;

__device__ inline float bf2f(unsigned short b) {
    union { unsigned u; float f; } v; v.u = ((unsigned)b) << 16; return v.f;
}
__device__ inline unsigned short f2bf(float f) {
    union { float f; unsigned u; } v; v.f = f;
    unsigned u = v.u;
    u += 0x7FFFu + ((u >> 16) & 1u);   // round-to-nearest-even
    return (unsigned short)(u >> 16);
}

// ---- prep: blocks [0,64) convert W fp32->bf16; [64,162) zero cnt ----
__global__ __launch_bounds__(256) void prep(const float* __restrict__ W,
                                            unsigned short* __restrict__ wb,
                                            int* __restrict__ cnt) {
    int bid = blockIdx.x;
    if (bid < CVT_BLOCKS) {
        int i = (bid * 256 + threadIdx.x) * 4;   // < 65536 always
        float4 f = *(const float4*)(W + i);
        ushort4 o;
        o.x = f2bf(f.x); o.y = f2bf(f.y); o.z = f2bf(f.z); o.w = f2bf(f.w);
        *(ushort4*)(wb + i) = o;
    } else {
        int t = (bid - CVT_BLOCKS) * 256 + threadIdx.x;
        if (t < N_NODES / 4) ((int4*)cnt)[t] = make_int4(0, 0, 0, 0);
    }
}

// ---- fused: blocks [0,3125) histogram; [3125, 3125+1563) MFMA GEMM ----
// GEMM: one wave computes a 16(M) x 256(N) strip of support = X @ W^T.
__global__ __launch_bounds__(256) void gemm_hist(
    const float* __restrict__ x,            // [N_NODES, 256] fp32
    const unsigned short* __restrict__ wb,  // [256, 256] bf16
    unsigned short* __restrict__ sb,        // [N_NODES, 256] bf16 out
    const int4* __restrict__ erow4,
    int* __restrict__ cnt)
{
    int bid = blockIdx.x;
    if (bid < HIST_BLOCKS) {
        int t = bid * 256 + threadIdx.x;     // exactly 800000 threads
        int4 r = erow4[t];
        atomicAdd(&cnt[r.x], 1);
        atomicAdd(&cnt[r.y], 1);
        atomicAdd(&cnt[r.z], 1);
        atomicAdd(&cnt[r.w], 1);
        return;
    }
    int wave = (int)((((bid - HIST_BLOCKS) * 256) + threadIdx.x) >> 6);
    int lane = threadIdx.x & 63;
    int m0 = wave << 4;
    if (m0 >= N_NODES) return;
    int quad = lane >> 4;
    int r16  = lane & 15;

    const f32x4* arow = (const f32x4*)(x + (size_t)(m0 + r16) * D + quad * 8);
    const unsigned short* bbase = wb + (size_t)r16 * D + quad * 8;

    f32x4 acc[16];
#pragma unroll
    for (int t = 0; t < 16; ++t) acc[t] = (f32x4){0.f, 0.f, 0.f, 0.f};

    for (int k0 = 0; k0 < D; k0 += 32) {
        // x is read exactly once per call -> non-temporal (keep L3 for support)
        f32x4 fa0 = __builtin_nontemporal_load(arow + (k0 >> 2));
        f32x4 fa1 = __builtin_nontemporal_load(arow + (k0 >> 2) + 1);
        bf16x8 a;
        a[0] = (short)f2bf(fa0[0]); a[1] = (short)f2bf(fa0[1]);
        a[2] = (short)f2bf(fa0[2]); a[3] = (short)f2bf(fa0[3]);
        a[4] = (short)f2bf(fa1[0]); a[5] = (short)f2bf(fa1[1]);
        a[6] = (short)f2bf(fa1[2]); a[7] = (short)f2bf(fa1[3]);
#pragma unroll
        for (int t = 0; t < 16; ++t) {
            bf16x8 b = *(const bf16x8*)(bbase + (size_t)t * 16 * D + k0);
            acc[t] = __builtin_amdgcn_mfma_f32_16x16x32_bf16(a, b, acc[t], 0, 0, 0);
        }
    }

#pragma unroll
    for (int t = 0; t < 16; ++t) {
#pragma unroll
        for (int r = 0; r < 4; ++r) {
            int row = m0 + quad * 4 + r;
            int col = t * 16 + r16;
            sb[(size_t)row * D + col] = f2bf(acc[t][r]);
        }
    }
}

// ================= scan chain (small) =================

__global__ __launch_bounds__(256) void scan_block(const int* __restrict__ cnt,
                                                  int* __restrict__ incl,
                                                  int* __restrict__ bsums, int n) {
    __shared__ int lds[256];
    int i = blockIdx.x * 256 + threadIdx.x;
    int v = (i < n) ? cnt[i] : 0;
    lds[threadIdx.x] = v;
    __syncthreads();
    for (int off = 1; off < 256; off <<= 1) {
        int t = (threadIdx.x >= (unsigned)off) ? lds[threadIdx.x - off] : 0;
        __syncthreads();
        lds[threadIdx.x] += t;
        __syncthreads();
    }
    if (i < n) incl[i] = lds[threadIdx.x];
    if (threadIdx.x == 255) bsums[blockIdx.x] = lds[255];
}

__global__ __launch_bounds__(512) void scan_sums(int* __restrict__ bsums, int nb) {
    __shared__ int lds[512];
    int v = (threadIdx.x < (unsigned)nb) ? bsums[threadIdx.x] : 0;
    lds[threadIdx.x] = v;
    __syncthreads();
    for (int off = 1; off < 512; off <<= 1) {
        int t = (threadIdx.x >= (unsigned)off) ? lds[threadIdx.x - off] : 0;
        __syncthreads();
        lds[threadIdx.x] += t;
        __syncthreads();
    }
    if (threadIdx.x < (unsigned)nb) bsums[threadIdx.x] = lds[threadIdx.x] - v;
}

__global__ __launch_bounds__(256) void finalize_scan(
    const int* __restrict__ cnt, const int* __restrict__ incl,
    const int* __restrict__ bsums, int* __restrict__ rowptr,
    int* __restrict__ next, int n) {
    int i = blockIdx.x * 256 + threadIdx.x;
    if (i >= n) return;
    int g = incl[i] + bsums[blockIdx.x];   // global inclusive
    rowptr[i + 1] = g;
    next[i] = g - cnt[i];                  // global exclusive
    if (i == 0) rowptr[0] = 0;
}

// ================= striped scatter, 4 edges/thread =================
__global__ __launch_bounds__(256) void scatter_striped(
    const int4* __restrict__ erow4, const int* __restrict__ ecol,
    const float* __restrict__ eval, int* __restrict__ next,
    int2* __restrict__ csr) {
    int t = blockIdx.x * 256 + threadIdx.x;   // group of 4 edges, exact fit
    int lo = (int)blockIdx.y * STRIPE;
    int hi = lo + STRIPE;
    int4 r4 = erow4[t];
    int rr[4] = {r4.x, r4.y, r4.z, r4.w};
#pragma unroll
    for (int j = 0; j < 4; ++j) {
        int r = rr[j];
        if (r >= lo && r < hi) {
            int e = t * 4 + j;
            int pos = atomicAdd(&next[r], 1);
            int2 p;
            p.x = ecol[e];
            p.y = __float_as_int(eval[e]);
            csr[pos] = p;
        }
    }
}

// ================= gather SpMM, unroll x4 =================
__global__ __launch_bounds__(256) void spmm_gather(
    const int* __restrict__ rowptr, const int2* __restrict__ csr,
    const unsigned short* __restrict__ sb, float* __restrict__ out) {
    int wave = (int)((blockIdx.x * blockDim.x + threadIdx.x) >> 6);
    int lane = threadIdx.x & 63;
    if (wave >= N_NODES) return;
    int beg = rowptr[wave], end = rowptr[wave + 1];
    f32x4 a0 = {0.f,0.f,0.f,0.f}, a1 = {0.f,0.f,0.f,0.f};
    f32x4 a2 = {0.f,0.f,0.f,0.f}, a3 = {0.f,0.f,0.f,0.f};
    const unsigned short* base = sb + lane * 4;
    int e = beg;
    for (; e + 3 < end; e += 4) {
        int2 p0 = csr[e];
        int2 p1 = csr[e + 1];
        int2 p2 = csr[e + 2];
        int2 p3 = csr[e + 3];
        ushort4 s0 = *(const ushort4*)(base + ((size_t)p0.x << 8));
        ushort4 s1 = *(const ushort4*)(base + ((size_t)p1.x << 8));
        ushort4 s2 = *(const ushort4*)(base + ((size_t)p2.x << 8));
        ushort4 s3 = *(const ushort4*)(base + ((size_t)p3.x << 8));
        float v0 = __int_as_float(p0.y), v1 = __int_as_float(p1.y);
        float v2 = __int_as_float(p2.y), v3 = __int_as_float(p3.y);
        a0[0] += v0 * bf2f(s0.x); a0[1] += v0 * bf2f(s0.y);
        a0[2] += v0 * bf2f(s0.z); a0[3] += v0 * bf2f(s0.w);
        a1[0] += v1 * bf2f(s1.x); a1[1] += v1 * bf2f(s1.y);
        a1[2] += v1 * bf2f(s1.z); a1[3] += v1 * bf2f(s1.w);
        a2[0] += v2 * bf2f(s2.x); a2[1] += v2 * bf2f(s2.y);
        a2[2] += v2 * bf2f(s2.z); a2[3] += v2 * bf2f(s2.w);
        a3[0] += v3 * bf2f(s3.x); a3[1] += v3 * bf2f(s3.y);
        a3[2] += v3 * bf2f(s3.z); a3[3] += v3 * bf2f(s3.w);
    }
    for (; e < end; ++e) {
        int2 p = csr[e];
        float v = __int_as_float(p.y);
        ushort4 s = *(const ushort4*)(base + ((size_t)p.x << 8));
        a0[0] += v * bf2f(s.x); a0[1] += v * bf2f(s.y);
        a0[2] += v * bf2f(s.z); a0[3] += v * bf2f(s.w);
    }
    f32x4 r = (a0 + a1) + (a2 + a3);
    // out is written once and never read -> non-temporal, keep L3 for support
    __builtin_nontemporal_store(r, (f32x4*)(out + (size_t)wave * D + lane * 4));
}

extern "C" void kernel_launch(void* const* d_in, const int* in_sizes, int n_in,
                              void* d_out, int out_size, void* d_ws, size_t ws_size,
                              hipStream_t stream) {
    const float* x    = (const float*)d_in[0];
    const float* W    = (const float*)d_in[1];
    const int*   erow = (const int*)d_in[2];
    const int*   ecol = (const int*)d_in[3];
    const float* eval = (const float*)d_in[4];
    float* out = (float*)d_out;

    // ---- workspace layout (bytes) ----
    char* ws = (char*)d_ws;
    unsigned short* wb     = (unsigned short*)(ws + 0);           // 131072
    unsigned short* sb     = (unsigned short*)(ws + 131072);      // 51,200,000
    int*            cnt    = (int*)(ws + 51331072);               // 400,000
    int*            incl   = (int*)(ws + 51731072);               // 400,000
    int*            rowptr = (int*)(ws + 52131072);               // 400,004
    int*            next   = (int*)(ws + 52531200);               // 400,000
    int*            bsums  = (int*)(ws + 52931200);               // 2,048
    int2*           csr    = (int2*)(ws + 52933632);              // 25,600,000
    // total ~78.6 MB

    const int nb = (N_NODES + 255) / 256;  // 391 scan blocks

    // ---- prep: cvt_w || zero cnt ----
    prep<<<CVT_BLOCKS + ZERO_BLOCKS, 256, 0, stream>>>(W, wb, cnt);

    // ---- fused: hist || GEMM ----
    gemm_hist<<<HIST_BLOCKS + GEMM_BLOCKS, 256, 0, stream>>>(
        x, wb, sb, (const int4*)erow, cnt);

    // ---- scan chain ----
    scan_block<<<nb, 256, 0, stream>>>(cnt, incl, bsums, N_NODES);
    scan_sums<<<1, 512, 0, stream>>>(bsums, nb);
    finalize_scan<<<nb, 256, 0, stream>>>(cnt, incl, bsums, rowptr, next, N_NODES);

    // ---- striped scatter ----
    {
        dim3 g(N_EDGES / 1024, N_STRIPES, 1);   // 3125 x 8
        scatter_striped<<<g, 256, 0, stream>>>((const int4*)erow, ecol, eval, next, csr);
    }

    // ---- gather SpMM ----
    spmm_gather<<<(N_NODES + 3) / 4, 256, 0, stream>>>(rowptr, csr, sb, out);
}